// Round 6
// baseline (140.954 us; speedup 1.0000x reference)
//
#include <hip/hip_runtime.h>

#define NROWS 8192
#define BQ    4096
#define DDIM  256
#define INV_T (1.0f/0.07f)
#define K2EXP (1.4426950408889634f/0.07f)   // log2(e)/T

typedef short bf16x8 __attribute__((ext_vector_type(8)));
typedef float f32x4  __attribute__((ext_vector_type(4)));
typedef unsigned short u16;

__device__ __forceinline__ u16 f2bf(float f) {
  unsigned u = __float_as_uint(f);
  u += 0x7fffu + ((u >> 16) & 1u);   // round-to-nearest-even
  return (u16)(u >> 16);
}

// ---------------- kernel 1: L2-normalize rows of [z_i; z_j], cast to bf16 ----
// Also zeroes the scalar output and the pos/neg atomic accumulators
// (stream-ordered; simloss/loss run after).
__global__ void norm_cast_kernel(const float* __restrict__ zi,
                                 const float* __restrict__ zj,
                                 u16* __restrict__ zb,
                                 float* __restrict__ posneg,   // 2*NROWS floats
                                 float* __restrict__ out) {
  if (blockIdx.x == 0 && threadIdx.x == 0) *out = 0.0f;
  if (blockIdx.x < 64) posneg[blockIdx.x * 256 + threadIdx.x] = 0.0f;
  int wave = threadIdx.x >> 6;
  int lane = threadIdx.x & 63;
  int row  = blockIdx.x * 4 + wave;            // one wave per row, 4 rows/block
  const float* src = (row < BQ) ? (zi + (size_t)row * DDIM)
                                : (zj + (size_t)(row - BQ) * DDIM);
  float4 v = ((const float4*)src)[lane];       // 64 lanes x float4 = 256
  float s = v.x*v.x + v.y*v.y + v.z*v.z + v.w*v.w;
  #pragma unroll
  for (int m = 32; m; m >>= 1) s += __shfl_xor(s, m, 64);
  float scale = 1.0f / fmaxf(sqrtf(s), 1e-12f);
  ushort4 o;
  o.x = f2bf(v.x * scale); o.y = f2bf(v.y * scale);
  o.z = f2bf(v.z * scale); o.w = f2bf(v.w * scale);
  ((ushort4*)(zb + (size_t)row * DDIM))[lane] = o;
}

// ---------------- kernel 2: fused sim GEMM + mask + pos/negexp partials ------
#define GL2LDS(gp, lp) \
  __builtin_amdgcn_global_load_lds((__attribute__((address_space(1))) void*)(gp), \
                                   (__attribute__((address_space(3))) void*)(lp), 16, 0, 0)

// LEDGER (do not re-try):
//  * r2 min-waves-4 launch bound: 128-reg cap spilled acc -> 620 MB scratch.
//  * r1/r3 deep REGISTER pipeline for B: ~210 live regs -> 34 MB scratch, 106us.
//  * r3 persistent 64KB A-tile: 2 blk/CU, occupancy 11%, 103us.
//  * r4 manual vmcnt(0)/s_barrier/sched_barrier dbuf: VGPR 180, occ 10.8%, 96us.
//  * r5 grid 512->1024 (16 col-splits): occupancy UNCHANGED 19.7%, dur
//    unchanged. Residency is capped at ~2 blocks/CU by something source-level
//    knobs don't reach. Occupancy cannot be raised; stop trying.
// This version: r0 inner loop VERBATIM (2 barriers/step, distance-0 staging,
// VGPR~128, measured 0 bank conflicts) but exploits SYMMETRY of sim = Z Z^T:
// only upper-triangular tile pairs (r<=c) are computed -- 2080 blocks instead
// of 4096 tile-visits. Tile (r,c) is bitwise-equal to (c,r)^T (same bf16
// operands, same K order), so its row-sums feed panel r and its column-sums
// feed panel c. Partials go through atomicAdd into single pos/neg arrays
// (8192 f32 each; ~65 adds per address over the whole kernel -> no hotspot),
// which also shrinks loss_kernel to 2 loads/row.
__global__ __launch_bounds__(256) void simloss_kernel(
    const u16* __restrict__ zb, const int* __restrict__ labels,
    float* __restrict__ pos, float* __restrict__ neg) {
  // row-major [128][32] bf16, chunk-SWIZZLED: row r's 8-elt chunk c lives at
  // slot c ^ ((r>>1)&3); spreads each quad's 16 lanes over all 16 bank-groups
  // -> 2-way = free. (measured: SQ_LDS_BANK_CONFLICT = 0)
  __shared__ __align__(16) u16 lsA[128 * 32];
  __shared__ __align__(16) u16 lsB[128 * 32];

  const int tid  = threadIdx.x;
  const int w    = tid >> 6;         // wave 0..3
  const int lane = tid & 63;
  const int ln   = lane & 15;        // MFMA n/m lane index
  const int qd   = lane >> 4;        // MFMA quad
  const int wr   = w >> 1;           // wave row (0..1) in 2x2 wave grid
  const int wc   = w & 1;            // wave col

  // triangular decode: blockIdx.x = u in [0,2080) -> (rb, cbk), rb <= cbk.
  // T(r) = r*(129-r)/2 tiles precede row r.
  const int u = blockIdx.x;
  int rb = (int)((129.0f - sqrtf((float)(16641 - 8 * u))) * 0.5f);
  while ((rb + 1) * (129 - (rb + 1)) / 2 <= u) ++rb;   // float-boundary fixup
  while (rb * (129 - rb) / 2 > u) --rb;
  const int cbk = rb + (u - rb * (129 - rb) / 2);
  const int r0 = rb * 128;
  const int c0 = cbk * 128;

  const int strow = lane >> 2;       // staging: 16 rows per load instr
  const int slot  = lane & 3;        // LDS chunk position this lane fills
  const int stk   = (slot ^ ((strow >> 1) & 3)) * 8;  // global chunk to fetch
  const int rdsw  = (ln >> 1) & 3;   // read-side swizzle key

  int rowidx[16], rowlab[16];
  #pragma unroll
  for (int ri = 0; ri < 4; ++ri)
    #pragma unroll
    for (int r = 0; r < 4; ++r) {
      int slt = ri * 4 + r;
      int row = r0 + wr * 64 + ri * 16 + qd * 4 + r;   // C/D: row = quad*4+reg
      rowidx[slt] = row;
      rowlab[slt] = labels[row & (BQ - 1)];            // concat labels = labels[row % B]
    }
  int colv[4], clab[4];
  #pragma unroll
  for (int mi = 0; mi < 4; ++mi) {
    colv[mi] = c0 + wc * 64 + mi * 16 + ln;            // C/D: col = lane&15
    clab[mi] = labels[colv[mi] & (BQ - 1)];
  }

  const f32x4 z4 = {0.f, 0.f, 0.f, 0.f};
  f32x4 acc[4][4];
  #pragma unroll
  for (int ri = 0; ri < 4; ++ri)
    #pragma unroll
    for (int mi = 0; mi < 4; ++mi) acc[ri][mi] = z4;

  for (int kk = 0; kk < 8; ++kk) {               // K = 256, BK = 32
    const int k0 = kk * 32;
    #pragma unroll
    for (int j = 0; j < 2; ++j) {                // wave stages 32 rows of A and B
      int rbase = w * 32 + j * 16;
      const u16* ga = zb + (size_t)(r0 + rbase + strow) * DDIM + k0 + stk;
      GL2LDS(ga, &lsA[rbase * 32]);
      const u16* gb = zb + (size_t)(c0 + rbase + strow) * DDIM + k0 + stk;
      GL2LDS(gb, &lsB[rbase * 32]);
    }
    __syncthreads();                             // drains vmcnt before barrier

    bf16x8 av[4], bv[4];
    #pragma unroll
    for (int ri = 0; ri < 4; ++ri)               // A[m=ln][k=qd*8+j], swizzled slot
      av[ri] = *(const bf16x8*)&lsA[(wr * 64 + ri * 16 + ln) * 32 + (qd ^ rdsw) * 8];
    #pragma unroll
    for (int mi = 0; mi < 4; ++mi)               // B[n=ln][k=qd*8+j] (B^T input)
      bv[mi] = *(const bf16x8*)&lsB[(wc * 64 + mi * 16 + ln) * 32 + (qd ^ rdsw) * 8];
    #pragma unroll
    for (int ri = 0; ri < 4; ++ri)
      #pragma unroll
      for (int mi = 0; mi < 4; ++mi)
        acc[ri][mi] = __builtin_amdgcn_mfma_f32_16x16x32_bf16(
            av[ri], bv[mi], acc[ri][mi], 0, 0, 0);
    __syncthreads();
  }

  // ---- fused epilogue ------------------------------------------------------
  float posA[16], negA[16];
  #pragma unroll
  for (int i = 0; i < 16; ++i) { posA[i] = 0.0f; negA[i] = 0.0f; }

  if (rb == cbk) {
    // diagonal tile: row-side only, with self-exclusion
    #pragma unroll
    for (int ri = 0; ri < 4; ++ri)
      #pragma unroll
      for (int mi = 0; mi < 4; ++mi) {
        f32x4 v = acc[ri][mi];
        #pragma unroll
        for (int r = 0; r < 4; ++r) {
          int slt = ri * 4 + r;
          float s = v[r];
          bool same = (rowlab[slt] == clab[mi]);
          bool diag = (rowidx[slt] == colv[mi]);
          posA[slt] += (same && !diag) ? s : 0.0f;
          negA[slt] += same ? 0.0f : __builtin_amdgcn_exp2f(s * K2EXP);
        }
      }
  } else {
    // off-diagonal tile: row-side (panel rb) AND column-side (panel cbk).
    // S[i][j] == S[j][i] bitwise, so column sums are panel-cbk row terms.
    float cpos[4], cneg[4];
    #pragma unroll
    for (int mi = 0; mi < 4; ++mi) { cpos[mi] = 0.0f; cneg[mi] = 0.0f; }
    #pragma unroll
    for (int ri = 0; ri < 4; ++ri)
      #pragma unroll
      for (int mi = 0; mi < 4; ++mi) {
        f32x4 v = acc[ri][mi];
        #pragma unroll
        for (int r = 0; r < 4; ++r) {
          int slt = ri * 4 + r;
          float s = v[r];
          bool same = (rowlab[slt] == clab[mi]);
          float e = same ? 0.0f : __builtin_amdgcn_exp2f(s * K2EXP);
          float p = same ? s : 0.0f;
          posA[slt] += p;  negA[slt] += e;
          cpos[mi]  += p;  cneg[mi]  += e;
        }
      }
    // column-side reduce: lane covers rows {qd*4..qd*4+3}+16*ri; sum the 4
    // quad groups (masks 16,32); then qd==0 lanes hold col totals.
    #pragma unroll
    for (int mi = 0; mi < 4; ++mi) {
      cpos[mi] += __shfl_xor(cpos[mi], 16, 64);
      cpos[mi] += __shfl_xor(cpos[mi], 32, 64);
      cneg[mi] += __shfl_xor(cneg[mi], 16, 64);
      cneg[mi] += __shfl_xor(cneg[mi], 32, 64);
    }
    if (qd == 0) {
      #pragma unroll
      for (int mi = 0; mi < 4; ++mi) {
        atomicAdd(&pos[colv[mi]], cpos[mi]);
        atomicAdd(&neg[colv[mi]], cneg[mi]);
      }
    }
  }

  // row-side reduce over the 16 lanes (ln) holding different cols of a row
  #pragma unroll
  for (int i = 0; i < 16; ++i) {
    #pragma unroll
    for (int m = 1; m < 16; m <<= 1) {
      posA[i] += __shfl_xor(posA[i], m, 64);
      negA[i] += __shfl_xor(negA[i], m, 64);
    }
  }
  if (ln == 0) {
    #pragma unroll
    for (int i = 0; i < 16; ++i) {
      atomicAdd(&pos[rowidx[i]], posA[i]);
      atomicAdd(&neg[rowidx[i]], negA[i]);
    }
  }
}

// ---------------- kernel 3: per-row loss + mean (parallel, atomic) -----------
__global__ void loss_kernel(const float* __restrict__ pos,
                            const float* __restrict__ neg,
                            float* __restrict__ out) {
  int row = blockIdx.x * 256 + threadIdx.x;      // 32 blocks x 256 threads
  float p = pos[row];
  float n = neg[row];
  float l = log1pf(expf(logf(n) - p * INV_T));
  #pragma unroll
  for (int m = 32; m; m >>= 1) l += __shfl_xor(l, m, 64);
  __shared__ float red[4];
  if ((threadIdx.x & 63) == 0) red[threadIdx.x >> 6] = l;
  __syncthreads();
  if (threadIdx.x == 0) {
    float tot = red[0] + red[1] + red[2] + red[3];
    atomicAdd(out, tot * (1.0f / NROWS));
  }
}

// ---------------- launcher ---------------------------------------------------
extern "C" void kernel_launch(void* const* d_in, const int* in_sizes, int n_in,
                              void* d_out, int out_size, void* d_ws, size_t ws_size,
                              hipStream_t stream) {
  const float* zi     = (const float*)d_in[0];
  const float* zj     = (const float*)d_in[1];
  const int*   labels = (const int*)d_in[2];
  float*       out    = (float*)d_out;

  char* w = (char*)d_ws;
  u16*   zb  = (u16*)w;                                          // 4 MB bf16 Z
  float* pos = (float*)(w + (size_t)NROWS * DDIM * sizeof(u16)); // 8192 f32
  float* neg = pos + NROWS;                                      // 8192 f32

  hipLaunchKernelGGL(norm_cast_kernel, dim3(2048), dim3(256), 0, stream,
                     zi, zj, zb, pos, out);
  hipLaunchKernelGGL(simloss_kernel, dim3(2080), dim3(256), 0, stream,
                     zb, labels, pos, neg);
  hipLaunchKernelGGL(loss_kernel, dim3(32), dim3(256), 0, stream,
                     pos, neg, out);
}